// Round 6
// baseline (201.073 us; speedup 1.0000x reference)
//
#include <hip/hip_runtime.h>

// B=2, C=256, H=W=64, P=3 -> Hp=Wp=62, Np=3844.
// X = A^T B via f16 MFMA hi/lo split (K=768), stored TILE-MAJOR.
// GEMM: 256x256 tile, BK=64, 8 waves (2x4), 8-phase-style schedule:
// per phase {ds_read frags | stage 1 half | barrier | lgkm(0) | 16 MFMA | counted vmcnt | barrier}.
// LDS K-half-major [buf][kh][256 rows][32 f16]: 64B row stride -> fragment
// b128 reads are bijective over 1KB (no bank conflicts, no swizzle needed);
// staging is linear on BOTH global and LDS sides.

typedef _Float16 half8 __attribute__((ext_vector_type(8)));
typedef float floatx4 __attribute__((ext_vector_type(4)));
typedef __attribute__((address_space(1))) const void gv_t;
typedef __attribute__((address_space(3))) void lv_t;

// ---------------------------------------------------------------------------
// prep: per-pixel L2 norm + f16 hi/lo split + pack [pix][768] PLAIN layout.
__global__ void prep_kernel(const float* __restrict__ df1, const float* __restrict__ df2,
                            _Float16* __restrict__ Apack, _Float16* __restrict__ Bpack) {
  __shared__ float red[128];
  const int tid = threadIdx.x, hf = tid >> 6, lane = tid & 63;
  int g = blockIdx.x * 64 + lane;           // pixel-task 0..16383
  int pix = g & 4095;
  int bm = g >> 12;
  int b = bm >> 1, m = bm & 1;              // m=0: df1 -> Bpack, m=1: df2 -> Apack
  const float* src = (m ? df2 : df1) + (size_t)b * 1048576 + pix;

  float ss = 0.f;
  for (int c = hf * 128; c < hf * 128 + 128; ++c) {
    float v = src[(size_t)c * 4096];
    ss += v * v;
  }
  red[tid] = ss;
  __syncthreads();
  float tot = red[lane] + red[lane + 64];
  float sc = 1.f / fmaxf(sqrtf(tot), 1e-12f);

  _Float16* dst = (m ? Apack : Bpack) + (size_t)b * 3145728 + (size_t)pix * 768;

  for (int c0 = hf * 128; c0 < hf * 128 + 128; c0 += 8) {
    half8 hi, lo;
#pragma unroll
    for (int j = 0; j < 8; ++j) {
      float v = src[(size_t)(c0 + j) * 4096] * sc;
      _Float16 h = (_Float16)v;
      hi[j] = h;
      lo[j] = (_Float16)(4096.f * (v - (float)h));
    }
    int o = (c0 >> 3) & 31;                 // octet 0..31 within a segment
    if (m) {  // A = [hi | lo | hi]
      *(half8*)(dst + o * 8) = hi;
      *(half8*)(dst + 256 + o * 8) = lo;
      *(half8*)(dst + 512 + o * 8) = hi;
    } else {  // B = [lo | hi | hi]
      *(half8*)(dst + o * 8) = lo;
      *(half8*)(dst + 256 + o * 8) = hi;
      *(half8*)(dst + 512 + o * 8) = hi;
    }
  }
}

// ---------------------------------------------------------------------------
__global__ __launch_bounds__(512, 2) void gemm_mfma(const _Float16* __restrict__ A,
                                                    const _Float16* __restrict__ B,
                                                    float* __restrict__ X) {
  __shared__ _Float16 As[2][2][256][32];    // [buf][khalf][row][32 f16] = 64 KB
  __shared__ _Float16 Bs[2][2][256][32];    // 64 KB

  int bid = blockIdx.x;                     // 256 blocks; bijective XCD swizzle
  int swb = (bid & 7) * 32 + (bid >> 3);
  int bx = swb & 15, by = swb >> 4;
  const int u0 = by << 8, v0 = bx << 8;

  const int tid = threadIdx.x, lane = tid & 63, wid = tid >> 6;
  const int wr = wid >> 2, wc = wid & 3;    // 2 x 4 waves; per-wave out 128x64
  const int frow = lane & 15, fhi = lane >> 4;

  floatx4 acc[8][4];
#pragma unroll
  for (int i = 0; i < 8; ++i)
#pragma unroll
    for (int j = 0; j < 4; ++j) acc[i][j] = (floatx4){0.f, 0.f, 0.f, 0.f};

  const _Float16* Abase = A + (size_t)u0 * 768;
  const _Float16* Bbase = B + (size_t)v0 * 768;

  // Stage one 16KB half: operand op's K-tile kt, K-half kh. 2 instr/thread;
  // LDS dest linear (wave-uniform + lane*16), global source linear.
#define STG(OPB, LDSB, kt, kh)                                                \
  {                                                                           \
    _Pragma("unroll") for (int i_ = 0; i_ < 2; ++i_) {                        \
      int c_ = i_ * 512 + tid;                                                \
      int r_ = c_ >> 2, s_ = c_ & 3;                                          \
      __builtin_amdgcn_global_load_lds(                                       \
          (gv_t*)(OPB + (size_t)r_ * 768 + (kt) * 64 + (kh) * 32 + s_ * 8),   \
          (lv_t*)(&LDSB[(kt) & 1][kh][0][0] + c_ * 8), 16, 0, 0);             \
    }                                                                         \
  }

  // prologue: K-tiles 0,1 fully staged (order: kh0(0) A,B; kh1(0); kh0(1); kh1(1))
  STG(Abase, As, 0, 0); STG(Bbase, Bs, 0, 0);
  STG(Abase, As, 0, 1); STG(Bbase, Bs, 0, 1);
  STG(Abase, As, 1, 0); STG(Bbase, Bs, 1, 0);
  STG(Abase, As, 1, 1); STG(Bbase, Bs, 1, 1);
  asm volatile("s_waitcnt vmcnt(12)" ::: "memory");   // kh0(0) A,B landed
  __builtin_amdgcn_sched_barrier(0);
  __builtin_amdgcn_s_barrier();

  half8 bf[4];

  for (int kt = 0; kt < 12; ++kt) {
    const int buf = kt & 1;
    const _Float16* LA0 = &As[buf][0][0][0];
    const _Float16* LB0 = &Bs[buf][0][0][0];
    const _Float16* LA1 = &As[buf][1][0][0];
    const _Float16* LB1 = &Bs[buf][1][0][0];
    half8 af[4];

    // ---------- P1: kk=0, mh=0 (acc rows 0-3), read B ----------
#pragma unroll
    for (int g = 0; g < 4; ++g)
      bf[g] = *(const half8*)(LB0 + (wc * 64 + g * 16 + frow) * 32 + fhi * 8);
#pragma unroll
    for (int f = 0; f < 4; ++f)
      af[f] = *(const half8*)(LA0 + (wr * 128 + f * 16 + frow) * 32 + fhi * 8);
    if (kt >= 1 && kt <= 10) STG(Abase, As, kt + 1, 1);
    __builtin_amdgcn_sched_barrier(0);
    __builtin_amdgcn_s_barrier();
    asm volatile("s_waitcnt lgkmcnt(0)" ::: "memory");
    __builtin_amdgcn_sched_barrier(0);
    __builtin_amdgcn_s_setprio(1);
#pragma unroll
    for (int f = 0; f < 4; ++f)
#pragma unroll
      for (int g = 0; g < 4; ++g)
        acc[f][g] = __builtin_amdgcn_mfma_f32_16x16x32_f16(af[f], bf[g], acc[f][g], 0, 0, 0);
    __builtin_amdgcn_s_setprio(0);
    __builtin_amdgcn_sched_barrier(0);
    __builtin_amdgcn_s_barrier();

    // ---------- P2: kk=0, mh=1 (acc rows 4-7), reuse bf ----------
#pragma unroll
    for (int f = 0; f < 4; ++f)
      af[f] = *(const half8*)(LA0 + (wr * 128 + 64 + f * 16 + frow) * 32 + fhi * 8);
    if (kt >= 1 && kt <= 10) STG(Bbase, Bs, kt + 1, 1);
    __builtin_amdgcn_sched_barrier(0);
    __builtin_amdgcn_s_barrier();
    asm volatile("s_waitcnt lgkmcnt(0)" ::: "memory");
    __builtin_amdgcn_sched_barrier(0);
    __builtin_amdgcn_s_setprio(1);
#pragma unroll
    for (int f = 0; f < 4; ++f)
#pragma unroll
      for (int g = 0; g < 4; ++g)
        acc[4 + f][g] = __builtin_amdgcn_mfma_f32_16x16x32_f16(af[f], bf[g], acc[4 + f][g], 0, 0, 0);
    __builtin_amdgcn_s_setprio(0);
    // covers kh1(kt+1) reads at P3(kt+1): everything through P2(kt-1) staged done
    if (kt == 11) asm volatile("s_waitcnt vmcnt(0)" ::: "memory");
    else          asm volatile("s_waitcnt vmcnt(8)" ::: "memory");
    __builtin_amdgcn_sched_barrier(0);
    __builtin_amdgcn_s_barrier();

    // ---------- P3: kk=1, mh=0, read B ----------
#pragma unroll
    for (int g = 0; g < 4; ++g)
      bf[g] = *(const half8*)(LB1 + (wc * 64 + g * 16 + frow) * 32 + fhi * 8);
#pragma unroll
    for (int f = 0; f < 4; ++f)
      af[f] = *(const half8*)(LA1 + (wr * 128 + f * 16 + frow) * 32 + fhi * 8);
    if (kt <= 9) STG(Abase, As, kt + 2, 0);
    __builtin_amdgcn_sched_barrier(0);
    __builtin_amdgcn_s_barrier();
    asm volatile("s_waitcnt lgkmcnt(0)" ::: "memory");
    __builtin_amdgcn_sched_barrier(0);
    __builtin_amdgcn_s_setprio(1);
#pragma unroll
    for (int f = 0; f < 4; ++f)
#pragma unroll
      for (int g = 0; g < 4; ++g)
        acc[f][g] = __builtin_amdgcn_mfma_f32_16x16x32_f16(af[f], bf[g], acc[f][g], 0, 0, 0);
    __builtin_amdgcn_s_setprio(0);
    __builtin_amdgcn_sched_barrier(0);
    __builtin_amdgcn_s_barrier();

    // ---------- P4: kk=1, mh=1, reuse bf ----------
#pragma unroll
    for (int f = 0; f < 4; ++f)
      af[f] = *(const half8*)(LA1 + (wr * 128 + 64 + f * 16 + frow) * 32 + fhi * 8);
    if (kt <= 9) STG(Bbase, Bs, kt + 2, 0);
    __builtin_amdgcn_sched_barrier(0);
    __builtin_amdgcn_s_barrier();
    asm volatile("s_waitcnt lgkmcnt(0)" ::: "memory");
    __builtin_amdgcn_sched_barrier(0);
    __builtin_amdgcn_s_setprio(1);
#pragma unroll
    for (int f = 0; f < 4; ++f)
#pragma unroll
      for (int g = 0; g < 4; ++g)
        acc[4 + f][g] = __builtin_amdgcn_mfma_f32_16x16x32_f16(af[f], bf[g], acc[4 + f][g], 0, 0, 0);
    __builtin_amdgcn_s_setprio(0);
    if (kt == 7) {  // cross terms (K<512) done -> scale by 2^-12 before hi*hi
#pragma unroll
      for (int i = 0; i < 8; ++i)
#pragma unroll
        for (int j = 0; j < 4; ++j)
#pragma unroll
          for (int r = 0; r < 4; ++r) acc[i][j][r] *= 0.000244140625f;
    }
    // covers kh0(kt+1) reads at P1(kt+1)
    if (kt <= 9)       asm volatile("s_waitcnt vmcnt(8)" ::: "memory");
    else if (kt == 10) asm volatile("s_waitcnt vmcnt(4)" ::: "memory");
    __builtin_amdgcn_sched_barrier(0);
    __builtin_amdgcn_s_barrier();
  }
#undef STG

  // epilogue: tile-major store. C/D layout: col(=v)=lane&15, row(=u)=4*fhi+r.
#pragma unroll
  for (int mr = 0; mr < 8; ++mr) {
    int u = u0 + wr * 128 + mr * 16 + fhi * 4;
    int a4 = u >> 6, ub = u & 63;
#pragma unroll
    for (int nr = 0; nr < 4; ++nr) {
      int v = v0 + wc * 64 + nr * 16 + frow;
      int c4 = v >> 6, vb = v & 63;
      float* p = X + ((size_t)(a4 * 64 + c4) << 12) + (ub << 6) + vb;
#pragma unroll
      for (int r = 0; r < 4; ++r) p[r * 64] = acc[mr][nr][r];
    }
  }
}

// ---------------------------------------------------------------------------
// corr_argmax: block (qi,pi) stages 3 diagonal 64x64 tiles, computes the
// 9-tap sums for all (pj,qj) in 62x62, partial-argmax over pj (first-max).
__global__ __launch_bounds__(256) void corr_argmax(const float* __restrict__ X,
                                                   float* __restrict__ pval,
                                                   int* __restrict__ pidx) {
  __shared__ float T[3][4096];
  __shared__ float mv[16][64];
  __shared__ int mi[16][64];
  const int qi = blockIdx.x, pi = blockIdx.y;
  const int t = threadIdx.x, lane = t & 63, wid = t >> 6;

#pragma unroll
  for (int di = 0; di < 3; ++di) {
    const float* src = X + ((size_t)((pi + di) * 64 + (qi + di)) << 12);
    for (int k = wid; k < 16; k += 4) {
      __builtin_amdgcn_global_load_lds((gv_t*)(src + k * 256 + lane * 4),
                                       (lv_t*)(&T[di][k * 256]), 16, 0, 0);
    }
  }
  __syncthreads();

  const int pg = t >> 4, qg = t & 15;
  const int pj0 = pg * 4, qj0 = qg * 4;

  float acc[4][4];
#pragma unroll
  for (int i = 0; i < 4; ++i)
#pragma unroll
    for (int j = 0; j < 4; ++j) acc[i][j] = 0.f;

#pragma unroll
  for (int di = 0; di < 3; ++di) {
    float v[6][8];
#pragma unroll
    for (int r = 0; r < 6; ++r) {
      int rr = pj0 + r; if (rr > 63) rr = 63;
      *(float4*)&v[r][0] = *(const float4*)&T[di][rr * 64 + qj0];
      *(float4*)&v[r][4] = *(const float4*)&T[di][rr * 64 + qj0 + 4];
    }
#pragma unroll
    for (int i = 0; i < 4; ++i)
#pragma unroll
      for (int j = 0; j < 4; ++j)
        acc[i][j] += v[i][j] + v[i + 1][j + 1] + v[i + 2][j + 2];
  }

  float bv[4]; int bp[4];
#pragma unroll
  for (int j = 0; j < 4; ++j) { bv[j] = -3.0e38f; bp[j] = 0; }
#pragma unroll
  for (int i = 0; i < 4; ++i) {
    bool pvalid = (pj0 + i) < 62;
#pragma unroll
    for (int j = 0; j < 4; ++j) {
      float val = pvalid ? acc[i][j] : -3.0e38f;
      if (val > bv[j]) { bv[j] = val; bp[j] = pj0 + i; }
    }
  }
#pragma unroll
  for (int j = 0; j < 4; ++j) { mv[pg][qj0 + j] = bv[j]; mi[pg][qj0 + j] = bp[j]; }
  __syncthreads();

  if (t < 62) {
    float best = -3.0e38f; int bpj = 0;
    for (int g = 0; g < 16; ++g) {
      float vv = mv[g][t];
      if (vv > best) { best = vv; bpj = mi[g][t]; }
    }
    int q = qi * 62 + t;
    pval[(size_t)pi * 3844 + q] = best;
    pidx[(size_t)pi * 3844 + q] = pi * 62 + bpj;
  }
}

// ---------------------------------------------------------------------------
__global__ void argmax_reduce(const float* __restrict__ pval, const int* __restrict__ pidx,
                              int* __restrict__ fidx) {
  int qq = blockIdx.x * 256 + threadIdx.x;
  if (qq >= 3844) return;
  float best = -3.0e38f;
  int bi = 0;
  for (int c = 0; c < 62; ++c) {
    float vv = pval[(size_t)c * 3844 + qq];
    if (vv > best) { best = vv; bi = pidx[(size_t)c * 3844 + qq]; }
  }
  fidx[qq] = bi;
}

// ---------------------------------------------------------------------------
__global__ void flow_kernel(const int* __restrict__ fidx, float* __restrict__ out) {
  int t = blockIdx.x * 256 + threadIdx.x;
  if (t >= 147456) return;
  int comp = t & 1;
  int w = (t >> 1) & 63;
  int h = (t >> 7) & 63;
  int s = (t >> 13) % 9;
  int b = t / 73728;
  int i = s / 3, j = s % 3;
  int y = h - i, x = w - j;
  float val = 0.f;
  if (y >= 0 && x >= 0 && y < 62 && x < 62) {
    int idx = fidx[b * 3844 + y * 62 + x];
    val = (comp == 0) ? (float)(idx % 62) - (float)x : (float)(idx / 62) - (float)y;
  }
  out[t] = val;
}

// ---------------------------------------------------------------------------
extern "C" void kernel_launch(void* const* d_in, const int* in_sizes, int n_in,
                              void* d_out, int out_size, void* d_ws, size_t ws_size,
                              hipStream_t stream) {
  const float* df1 = (const float*)d_in[0];  // input  -> B operand (columns v)
  const float* df2 = (const float*)d_in[1];  // ref    -> A operand (rows u)
  float* out = (float*)d_out;

  char* ws = (char*)d_ws;
  _Float16* Apack = (_Float16*)ws;                       // 2*4096*768 f16
  _Float16* Bpack = (_Float16*)(ws + 12582912);
  float* X = (float*)(ws + 25165824);                    // 64 MiB tile-major
  float* pval = (float*)(ws + 25165824 + 67108864);      // 62*3844 f32
  int* pidx = (int*)((char*)pval + 953312);
  int* fidx = (int*)((char*)pidx + 953312);              // 2*3844 int

  prep_kernel<<<256, 128, 0, stream>>>(df1, df2, Apack, Bpack);

  const size_t BATCH_STRIDE = 3145728;  // f16 elements per batch per operand
  for (int b = 0; b < 2; ++b) {
    gemm_mfma<<<256, 512, 0, stream>>>(Apack + (size_t)b * BATCH_STRIDE,
                                       Bpack + (size_t)b * BATCH_STRIDE, X);
    corr_argmax<<<dim3(62, 62), 256, 0, stream>>>(X, pval, pidx);
    argmax_reduce<<<16, 256, 0, stream>>>(pval, pidx, fidx + b * 3844);
  }

  flow_kernel<<<576, 256, 0, stream>>>(fidx, out);
}

// Round 7
// 172.114 us; speedup vs baseline: 1.1683x; 1.1683x over previous
//
#include <hip/hip_runtime.h>

// B=2, C=256, H=W=64, P=3 -> Hp=Wp=62, Np=3844.
// X = A^T B via f16 MFMA hi/lo split (K=768), stored TILE-MAJOR.
// GEMM: 256x256 tile, BK=64, 8 waves (2x4), 4 phases/kt, counted vmcnt.
// LDS [buf][kh][256][32] f16; 16B slots XOR-swizzled by ((row>>1)&3),
// pre-applied at pack time so staging is linear on both sides (rule #21).
// corr: di/dj taps are separable -> Tsum = T0+T1+T2 in LDS, 3-tap diagonal.

typedef _Float16 half8 __attribute__((ext_vector_type(8)));
typedef float floatx4 __attribute__((ext_vector_type(4)));
typedef __attribute__((address_space(1))) const void gv_t;
typedef __attribute__((address_space(3))) void lv_t;

// ---------------------------------------------------------------------------
// prep: per-pixel L2 norm + f16 hi/lo split + pack [pix][768] with 4-slot XOR
// pre-swizzle: within each 32-f16 (kt,kh) group, octet o -> o^((pix>>1)&3).
__global__ void prep_kernel(const float* __restrict__ df1, const float* __restrict__ df2,
                            _Float16* __restrict__ Apack, _Float16* __restrict__ Bpack) {
  __shared__ float red[128];
  const int tid = threadIdx.x, hf = tid >> 6, lane = tid & 63;
  int g = blockIdx.x * 64 + lane;           // pixel-task 0..16383
  int pix = g & 4095;
  int bm = g >> 12;
  int b = bm >> 1, m = bm & 1;              // m=0: df1 -> Bpack, m=1: df2 -> Apack
  const float* src = (m ? df2 : df1) + (size_t)b * 1048576 + pix;

  float ss = 0.f;
  for (int c = hf * 128; c < hf * 128 + 128; ++c) {
    float v = src[(size_t)c * 4096];
    ss += v * v;
  }
  red[tid] = ss;
  __syncthreads();
  float tot = red[lane] + red[lane + 64];
  float sc = 1.f / fmaxf(sqrtf(tot), 1e-12f);

  _Float16* dst = (m ? Apack : Bpack) + (size_t)b * 3145728 + (size_t)pix * 768;
  const int swz = (pix >> 1) & 3;

  for (int c0 = hf * 128; c0 < hf * 128 + 128; c0 += 8) {
    half8 hi, lo;
#pragma unroll
    for (int j = 0; j < 8; ++j) {
      float v = src[(size_t)(c0 + j) * 4096] * sc;
      _Float16 h = (_Float16)v;
      hi[j] = h;
      lo[j] = (_Float16)(4096.f * (v - (float)h));
    }
    int o = (c0 >> 3) & 31;                 // octet 0..31 within a segment
    int oS = (o & ~3) | ((o & 3) ^ swz);    // XOR within each 4-octet group
    if (m) {  // A = [hi | lo | hi]
      *(half8*)(dst + oS * 8) = hi;
      *(half8*)(dst + 256 + oS * 8) = lo;
      *(half8*)(dst + 512 + oS * 8) = hi;
    } else {  // B = [lo | hi | hi]
      *(half8*)(dst + oS * 8) = lo;
      *(half8*)(dst + 256 + oS * 8) = hi;
      *(half8*)(dst + 512 + oS * 8) = hi;
    }
  }
}

// ---------------------------------------------------------------------------
__global__ __launch_bounds__(512, 2) void gemm_mfma(const _Float16* __restrict__ A,
                                                    const _Float16* __restrict__ B,
                                                    float* __restrict__ X) {
  __shared__ _Float16 As[2][2][256][32];    // [buf][khalf][row][32 f16] = 64 KB
  __shared__ _Float16 Bs[2][2][256][32];    // 64 KB

  int bid = blockIdx.x;                     // 256 blocks; bijective XCD swizzle
  int swb = (bid & 7) * 32 + (bid >> 3);
  int bx = swb & 15, by = swb >> 4;
  const int u0 = by << 8, v0 = bx << 8;

  const int tid = threadIdx.x, lane = tid & 63, wid = tid >> 6;
  const int wr = wid >> 2, wc = wid & 3;    // 2 x 4 waves; per-wave out 128x64
  const int frow = lane & 15, fhi = lane >> 4;
  const int fsw = (lane >> 1) & 3;          // == (row>>1)&3 (bases are 16-mult)

  floatx4 acc[8][4];
#pragma unroll
  for (int i = 0; i < 8; ++i)
#pragma unroll
    for (int j = 0; j < 4; ++j) acc[i][j] = (floatx4){0.f, 0.f, 0.f, 0.f};

  const _Float16* Abase = A + (size_t)u0 * 768;
  const _Float16* Bbase = B + (size_t)v0 * 768;

#define STG(OPB, LDSB, kt, kh)                                                \
  {                                                                           \
    _Pragma("unroll") for (int i_ = 0; i_ < 2; ++i_) {                        \
      int c_ = i_ * 512 + tid;                                                \
      int r_ = c_ >> 2, s_ = c_ & 3;                                          \
      __builtin_amdgcn_global_load_lds(                                       \
          (gv_t*)(OPB + (size_t)r_ * 768 + (kt) * 64 + (kh) * 32 + s_ * 8),   \
          (lv_t*)(&LDSB[(kt) & 1][kh][0][0] + c_ * 8), 16, 0, 0);             \
    }                                                                         \
  }

  // prologue: K-tiles 0,1 fully staged
  STG(Abase, As, 0, 0); STG(Bbase, Bs, 0, 0);
  STG(Abase, As, 0, 1); STG(Bbase, Bs, 0, 1);
  STG(Abase, As, 1, 0); STG(Bbase, Bs, 1, 0);
  STG(Abase, As, 1, 1); STG(Bbase, Bs, 1, 1);
  asm volatile("s_waitcnt vmcnt(12)" ::: "memory");   // kh0(0) A,B landed
  __builtin_amdgcn_sched_barrier(0);
  __builtin_amdgcn_s_barrier();

  half8 bf[4];

  for (int kt = 0; kt < 12; ++kt) {
    const int buf = kt & 1;
    const _Float16* LA0 = &As[buf][0][0][0];
    const _Float16* LB0 = &Bs[buf][0][0][0];
    const _Float16* LA1 = &As[buf][1][0][0];
    const _Float16* LB1 = &Bs[buf][1][0][0];
    half8 af[4];

    // ---------- P1: kk=0, mh=0 (acc rows 0-3), read B ----------
#pragma unroll
    for (int g = 0; g < 4; ++g)
      bf[g] = *(const half8*)(LB0 + (wc * 64 + g * 16 + frow) * 32 + ((fhi ^ fsw)) * 8);
#pragma unroll
    for (int f = 0; f < 4; ++f)
      af[f] = *(const half8*)(LA0 + (wr * 128 + f * 16 + frow) * 32 + ((fhi ^ fsw)) * 8);
    if (kt >= 1 && kt <= 10) STG(Abase, As, kt + 1, 1);
    __builtin_amdgcn_sched_barrier(0);
    __builtin_amdgcn_s_barrier();
    asm volatile("s_waitcnt lgkmcnt(0)" ::: "memory");
    __builtin_amdgcn_sched_barrier(0);
    __builtin_amdgcn_s_setprio(1);
#pragma unroll
    for (int f = 0; f < 4; ++f)
#pragma unroll
      for (int g = 0; g < 4; ++g)
        acc[f][g] = __builtin_amdgcn_mfma_f32_16x16x32_f16(af[f], bf[g], acc[f][g], 0, 0, 0);
    __builtin_amdgcn_s_setprio(0);
    __builtin_amdgcn_sched_barrier(0);
    __builtin_amdgcn_s_barrier();

    // ---------- P2: kk=0, mh=1 (acc rows 4-7), reuse bf ----------
#pragma unroll
    for (int f = 0; f < 4; ++f)
      af[f] = *(const half8*)(LA0 + (wr * 128 + 64 + f * 16 + frow) * 32 + ((fhi ^ fsw)) * 8);
    if (kt >= 1 && kt <= 10) STG(Bbase, Bs, kt + 1, 1);
    __builtin_amdgcn_sched_barrier(0);
    __builtin_amdgcn_s_barrier();
    asm volatile("s_waitcnt lgkmcnt(0)" ::: "memory");
    __builtin_amdgcn_sched_barrier(0);
    __builtin_amdgcn_s_setprio(1);
#pragma unroll
    for (int f = 0; f < 4; ++f)
#pragma unroll
      for (int g = 0; g < 4; ++g)
        acc[4 + f][g] = __builtin_amdgcn_mfma_f32_16x16x32_f16(af[f], bf[g], acc[4 + f][g], 0, 0, 0);
    __builtin_amdgcn_s_setprio(0);
    if (kt == 11) asm volatile("s_waitcnt vmcnt(0)" ::: "memory");
    else          asm volatile("s_waitcnt vmcnt(8)" ::: "memory");
    __builtin_amdgcn_sched_barrier(0);
    __builtin_amdgcn_s_barrier();

    // ---------- P3: kk=1, mh=0, read B ----------
#pragma unroll
    for (int g = 0; g < 4; ++g)
      bf[g] = *(const half8*)(LB1 + (wc * 64 + g * 16 + frow) * 32 + ((fhi ^ fsw)) * 8);
#pragma unroll
    for (int f = 0; f < 4; ++f)
      af[f] = *(const half8*)(LA1 + (wr * 128 + f * 16 + frow) * 32 + ((fhi ^ fsw)) * 8);
    if (kt <= 9) STG(Abase, As, kt + 2, 0);
    __builtin_amdgcn_sched_barrier(0);
    __builtin_amdgcn_s_barrier();
    asm volatile("s_waitcnt lgkmcnt(0)" ::: "memory");
    __builtin_amdgcn_sched_barrier(0);
    __builtin_amdgcn_s_setprio(1);
#pragma unroll
    for (int f = 0; f < 4; ++f)
#pragma unroll
      for (int g = 0; g < 4; ++g)
        acc[f][g] = __builtin_amdgcn_mfma_f32_16x16x32_f16(af[f], bf[g], acc[f][g], 0, 0, 0);
    __builtin_amdgcn_s_setprio(0);
    __builtin_amdgcn_sched_barrier(0);
    __builtin_amdgcn_s_barrier();

    // ---------- P4: kk=1, mh=1, reuse bf ----------
#pragma unroll
    for (int f = 0; f < 4; ++f)
      af[f] = *(const half8*)(LA1 + (wr * 128 + 64 + f * 16 + frow) * 32 + ((fhi ^ fsw)) * 8);
    if (kt <= 9) STG(Bbase, Bs, kt + 2, 0);
    __builtin_amdgcn_sched_barrier(0);
    __builtin_amdgcn_s_barrier();
    asm volatile("s_waitcnt lgkmcnt(0)" ::: "memory");
    __builtin_amdgcn_sched_barrier(0);
    __builtin_amdgcn_s_setprio(1);
#pragma unroll
    for (int f = 0; f < 4; ++f)
#pragma unroll
      for (int g = 0; g < 4; ++g)
        acc[4 + f][g] = __builtin_amdgcn_mfma_f32_16x16x32_f16(af[f], bf[g], acc[4 + f][g], 0, 0, 0);
    __builtin_amdgcn_s_setprio(0);
    if (kt == 7) {  // cross terms (K<512) done -> scale by 2^-12 before hi*hi
#pragma unroll
      for (int i = 0; i < 8; ++i)
#pragma unroll
        for (int j = 0; j < 4; ++j)
#pragma unroll
          for (int r = 0; r < 4; ++r) acc[i][j][r] *= 0.000244140625f;
    }
    if (kt <= 9)       asm volatile("s_waitcnt vmcnt(8)" ::: "memory");
    else if (kt == 10) asm volatile("s_waitcnt vmcnt(4)" ::: "memory");
    __builtin_amdgcn_sched_barrier(0);
    __builtin_amdgcn_s_barrier();
  }
#undef STG

  // epilogue: tile-major store. C/D layout: col(=v)=lane&15, row(=u)=4*fhi+r.
#pragma unroll
  for (int mr = 0; mr < 8; ++mr) {
    int u = u0 + wr * 128 + mr * 16 + fhi * 4;
    int a4 = u >> 6, ub = u & 63;
#pragma unroll
    for (int nr = 0; nr < 4; ++nr) {
      int v = v0 + wc * 64 + nr * 16 + frow;
      int c4 = v >> 6, vb = v & 63;
      float* p = X + ((size_t)(a4 * 64 + c4) << 12) + (ub << 6) + vb;
#pragma unroll
      for (int r = 0; r < 4; ++r) p[r * 64] = acc[mr][nr][r];
    }
  }
}

// ---------------------------------------------------------------------------
// corr_argmax: block (qi,pi). di/dj separable: Tsum = sum_di tile(pi+di,qi+di)
// built via register staging (3 global float4 per element-chunk), then
// corr[pj][qj] = sum_dj Tsum[pj+dj][qj+dj]; partial argmax over pj.
__global__ __launch_bounds__(256) void corr_argmax(const float* __restrict__ X,
                                                   float* __restrict__ pval,
                                                   int* __restrict__ pidx) {
  __shared__ float Tsum[4096];
  __shared__ float mv[16][64];
  __shared__ int mi[16][64];
  const int qi = blockIdx.x, pi = blockIdx.y;
  const int t = threadIdx.x;

  const float* t0 = X + ((size_t)((pi + 0) * 64 + (qi + 0)) << 12);
  const float* t1 = X + ((size_t)((pi + 1) * 64 + (qi + 1)) << 12);
  const float* t2 = X + ((size_t)((pi + 2) * 64 + (qi + 2)) << 12);
#pragma unroll
  for (int k = 0; k < 4; ++k) {
    int e = k * 1024 + t * 4;
    float4 a = *(const float4*)(t0 + e);
    float4 b = *(const float4*)(t1 + e);
    float4 c = *(const float4*)(t2 + e);
    float4 s = {a.x + b.x + c.x, a.y + b.y + c.y, a.z + b.z + c.z, a.w + b.w + c.w};
    *(float4*)&Tsum[e] = s;   // byte off = k*4096 + t*16 -> conflict-free
  }
  __syncthreads();

  const int pg = t >> 4, qg = t & 15;
  const int pj0 = pg * 4, qj0 = qg * 4;

  float v[6][8];
#pragma unroll
  for (int r = 0; r < 6; ++r) {
    int rr = pj0 + r; if (rr > 63) rr = 63;   // clamped rows feed only invalid pj
    *(float4*)&v[r][0] = *(const float4*)&Tsum[rr * 64 + qj0];
    *(float4*)&v[r][4] = *(const float4*)&Tsum[rr * 64 + qj0 + 4];  // overreads feed only invalid qj (mv follows Tsum -> in-bounds)
  }

  float acc[4][4];
#pragma unroll
  for (int i = 0; i < 4; ++i)
#pragma unroll
    for (int j = 0; j < 4; ++j)
      acc[i][j] = v[i][j] + v[i + 1][j + 1] + v[i + 2][j + 2];

  float bv[4]; int bp[4];
#pragma unroll
  for (int j = 0; j < 4; ++j) { bv[j] = -3.0e38f; bp[j] = 0; }
#pragma unroll
  for (int i = 0; i < 4; ++i) {
    bool pvalid = (pj0 + i) < 62;
#pragma unroll
    for (int j = 0; j < 4; ++j) {
      float val = pvalid ? acc[i][j] : -3.0e38f;
      if (val > bv[j]) { bv[j] = val; bp[j] = pj0 + i; }   // ascending pj, strict >
    }
  }
#pragma unroll
  for (int j = 0; j < 4; ++j) { mv[pg][qj0 + j] = bv[j]; mi[pg][qj0 + j] = bp[j]; }
  __syncthreads();

  if (t < 62) {
    float best = -3.0e38f; int bpj = 0;
    for (int g = 0; g < 16; ++g) {           // ascending g = ascending pj
      float vv = mv[g][t];
      if (vv > best) { best = vv; bpj = mi[g][t]; }
    }
    int q = qi * 62 + t;
    pval[(size_t)pi * 3844 + q] = best;
    pidx[(size_t)pi * 3844 + q] = pi * 62 + bpj;
  }
}

// ---------------------------------------------------------------------------
// reduce both batches in one dispatch (grid 32): qq2 in [0, 7688)
__global__ void argmax_reduce(const float* __restrict__ pval0, const int* __restrict__ pidx0,
                              const float* __restrict__ pval1, const int* __restrict__ pidx1,
                              int* __restrict__ fidx) {
  int qq2 = blockIdx.x * 256 + threadIdx.x;
  if (qq2 >= 7688) return;
  int b = qq2 >= 3844;
  int qq = qq2 - b * 3844;
  const float* pv = b ? pval1 : pval0;
  const int* px = b ? pidx1 : pidx0;
  float best = -3.0e38f;
  int bi = 0;
  for (int c = 0; c < 62; ++c) {
    float vv = pv[(size_t)c * 3844 + qq];
    if (vv > best) { best = vv; bi = px[(size_t)c * 3844 + qq]; }
  }
  fidx[qq2] = bi;
}

// ---------------------------------------------------------------------------
__global__ void flow_kernel(const int* __restrict__ fidx, float* __restrict__ out) {
  int t = blockIdx.x * 256 + threadIdx.x;
  if (t >= 147456) return;
  int comp = t & 1;
  int w = (t >> 1) & 63;
  int h = (t >> 7) & 63;
  int s = (t >> 13) % 9;
  int b = t / 73728;
  int i = s / 3, j = s % 3;
  int y = h - i, x = w - j;
  float val = 0.f;
  if (y >= 0 && x >= 0 && y < 62 && x < 62) {
    int idx = fidx[b * 3844 + y * 62 + x];
    val = (comp == 0) ? (float)(idx % 62) - (float)x : (float)(idx / 62) - (float)y;
  }
  out[t] = val;
}

// ---------------------------------------------------------------------------
extern "C" void kernel_launch(void* const* d_in, const int* in_sizes, int n_in,
                              void* d_out, int out_size, void* d_ws, size_t ws_size,
                              hipStream_t stream) {
  const float* df1 = (const float*)d_in[0];  // input  -> B operand (columns v)
  const float* df2 = (const float*)d_in[1];  // ref    -> A operand (rows u)
  float* out = (float*)d_out;

  char* ws = (char*)d_ws;
  _Float16* Apack = (_Float16*)ws;                       // 2*4096*768 f16
  _Float16* Bpack = (_Float16*)(ws + 12582912);
  float* X = (float*)(ws + 25165824);                    // 64 MiB tile-major
  float* pval0 = (float*)(ws + 25165824 + 67108864);     // 62*3844 f32
  int* pidx0 = (int*)((char*)pval0 + 953312);
  int* fidx = (int*)((char*)pidx0 + 953312);             // 2*3844 int
  // pval1/pidx1 alias onto Apack: Apack is dead after gemm(b=1), and
  // corr_argmax(b=1) runs strictly after it (stream order).
  float* pval1 = (float*)Apack;
  int* pidx1 = (int*)((char*)Apack + 953312);

  prep_kernel<<<256, 128, 0, stream>>>(df1, df2, Apack, Bpack);

  const size_t BATCH_STRIDE = 3145728;  // f16 elements per batch per operand
  gemm_mfma<<<256, 512, 0, stream>>>(Apack, Bpack, X);
  corr_argmax<<<dim3(62, 62), 256, 0, stream>>>(X, pval0, pidx0);
  gemm_mfma<<<256, 512, 0, stream>>>(Apack + BATCH_STRIDE, Bpack + BATCH_STRIDE, X);
  corr_argmax<<<dim3(62, 62), 256, 0, stream>>>(X, pval1, pidx1);

  argmax_reduce<<<32, 256, 0, stream>>>(pval0, pidx0, pval1, pidx1, fidx);
  flow_kernel<<<576, 256, 0, stream>>>(fidx, out);
}